// Round 14
// baseline (71.127 us; speedup 1.0000x reference)
//
#include <hip/hip_runtime.h>
#include <math.h>

// r11 lineage (PASSING, 60.6us). Two deltas, both inside the validated
// one-tap-set-per-thread regime (multi-juv and multi-gi per-thread regimes
// are abandoned: r1/r13 fail at 0.402, r5/6/7 at 0.494, cause unlocated):
//   1. C: 16 -> 32 channels per block (halves block count -> halves per-chunk
//      barriers and total tap-trig VALU; LDS 50.3 KB -> 3 blocks/CU).
//   2. Tap math hoisted ABOVE __syncthreads so per-thread trig overlaps the
//      staging latency instead of serializing after the barrier.
//
// out flat: ((((o*8 + gi)*128 + ic)*8 + j)*7 + u)*7 + v
// sig flat: ((o*128 + ic)*8 + d)*49 + h*7 + w

constexpr int BLOCK = 448;          // 7 waves; tids 392..447 stage-only
constexpr int JUV = 392;
constexpr int C = 32;               // channels per block (32 | 128 -> one 'o')
constexpr int PAD = 16;             // front/back pad floats (covers b in [-8, 399+8])

__global__ __launch_bounds__(BLOCK)
void lift14(const float* __restrict__ sig, float* __restrict__ out) {
  __shared__ __align__(16) float lds_raw[PAD + C * JUV + PAD];
  float* lds = lds_raw + PAD;

  const int bid   = blockIdx.x;                      // 0..4095
  const int gi    = (bid >> 3) & 7;                  // 0..7
  const int chunk = ((bid >> 6) << 3) | (bid & 7);   // 0..511, same-XCD + adjacent sharers
  const int c0    = chunk * C;

  // ---- zero pads, then stage chunk with coalesced float4 (r9 pattern) ----
  if (threadIdx.x < PAD) {
    lds_raw[threadIdx.x] = 0.0f;
    lds_raw[PAD + C * JUV + threadIdx.x] = 0.0f;
  }
  {
    const float4* src4 = (const float4*)(sig + (size_t)c0 * JUV);
    float4* dst4 = (float4*)lds;
    #pragma unroll
    for (int k = 0; k < C * JUV / 4 / BLOCK; ++k)    // 3136/448 = 7 exact
      dst4[threadIdx.x + k * BLOCK] = src4[threadIdx.x + k * BLOCK];
  }

  // ---- tap computation BEFORE the barrier (overlaps staging latency) ----
  const int juv = threadIdx.x;
  const bool active = juv < JUV;

  float eW = 0.0f, w00 = 0.0f, w01 = 0.0f, w10 = 0.0f, w11 = 0.0f;
  int eOff = 0, bb = 0;
  const bool even = (gi & 1) == 0;

  if (active) {
    int j  = juv / 49;
    int uv = juv - j * 49;
    int uu = uv / 7;
    int vv = uv - uu * 7;

    // ================= tap computation (verified math, rounds 2-11) =======
    const float TWO_PI_F = 6.28318530717958647692f;
    const float STEP = TWO_PI_F / 8.0f;

    float ti = (float)gi * STEP;
    float tj = (float)j  * STEP;

    // ---- D (group) axis ----
    float tH = fmodf(tj - ti, TWO_PI_F);
    if (tH < 0.0f) tH += TWO_PI_F;
    const float largest = TWO_PI_F * 7.0f / 8.0f;
    float cD = 2.0f * tH / largest - 1.0f;
    float posD = (cD + 1.0f) * 0.5f * 7.0f;
    float flD = floorf(posD);
    float fd  = posD - flD;
    int dlo = (int)flD, dhi = dlo + 1;
    float wd0 = (dlo >= 0 && dlo <= 7) ? (1.0f - fd) : 0.0f;
    float wd1 = (dhi >= 0 && dhi <= 7) ? fd : 0.0f;
    int d0 = min(max(dlo, 0), 7) * 49;
    int d1 = min(max(dhi, 0), 7) * 49;

    // ---- rotation by inverse(e_i) ----
    float inv = fmodf(-ti, TWO_PI_F);
    if (inv < 0.0f) inv += TWO_PI_F;
    float cs = cosf(inv), sn = sinf(inv);
    float gx = (float)(uu - 3) * (1.0f / 3.0f);
    float gy = (float)(vv - 3) * (1.0f / 3.0f);
    float rx = cs * gx - sn * gy;
    float ry = sn * gx + cs * gy;

    // ---- H axis (rx) ----
    float posH = (rx + 1.0f) * 0.5f * 6.0f;
    float flH = floorf(posH);
    float fh  = posH - flH;
    int hlo = (int)flH, hhi = hlo + 1;
    float wh0 = (hlo >= 0 && hlo <= 6) ? (1.0f - fh) : 0.0f;
    float wh1 = (hhi >= 0 && hhi <= 6) ? fh : 0.0f;
    int h0 = min(max(hlo, 0), 6) * 7;
    int h1 = min(max(hhi, 0), 6) * 7;

    // ---- W axis (ry) ----
    float posW = (ry + 1.0f) * 0.5f * 6.0f;
    float flW = floorf(posW);
    float fw  = posW - flW;
    int wlo = (int)flW, whi = wlo + 1;
    float wq0 = (wlo >= 0 && wlo <= 6) ? (1.0f - fw) : 0.0f;
    float wq1 = (whi >= 0 && whi <= 6) ? fw : 0.0f;
    int q0 = min(max(wlo, 0), 6);
    int q1 = min(max(whi, 0), 6);
    // ======================================================================

    // dominant d slice (validated r4/r8-r11)
    float Wd; int db;
    if (wd1 > wd0) { Wd = wd1; db = d1; } else { Wd = wd0; db = d0; }

    if (even) {
      float Wh; int hb;
      if (wh1 > wh0) { Wh = wh1; hb = h1; } else { Wh = wh0; hb = h0; }
      float Ww; int qb;
      if (wq1 > wq0) { Ww = wq1; qb = q1; } else { Ww = wq0; qb = q0; }
      eW   = Wd * Wh * Ww;
      eOff = db + hb + qb;
    } else {
      w00 = Wd * wh0 * wq0;  w01 = Wd * wh0 * wq1;
      w10 = Wd * wh1 * wq0;  w11 = Wd * wh1 * wq1;
      bb  = db + hlo * 7 + wlo;   // unclamped; pads cover OOB (validated r10)
    }
  }

  __syncthreads();

  if (!active) return;

  const int o   = c0 >> 7;
  const int ic0 = c0 & 127;
  float* op = out + (size_t)((o * 8 + gi) * 128 + ic0) * JUV + juv;

  if (even) {
    #pragma unroll
    for (int c = 0; c < C; ++c) {
      __builtin_nontemporal_store(lds[c * JUV + eOff] * eW, op);
      op += JUV;
    }
  } else {
    #pragma unroll
    for (int c = 0; c < C; ++c) {
      const float* s = lds + c * JUV + bb;
      float acc = s[0] * w00 + s[1] * w01
                + s[7] * w10 + s[8] * w11;
      __builtin_nontemporal_store(acc, op);
      op += JUV;
    }
  }
}

extern "C" void kernel_launch(void* const* d_in, const int* in_sizes, int n_in,
                              void* d_out, int out_size, void* d_ws, size_t ws_size,
                              hipStream_t stream) {
  const float* w = (const float*)d_in[0];
  float* out = (float*)d_out;
  const int blocks = 8 * (128 * 128 / C);   // 4096
  hipLaunchKernelGGL(lift14, dim3(blocks), dim3(BLOCK), 0, stream, w, out);
}

// Round 15
// 45.139 us; speedup vs baseline: 1.5757x; 1.5757x over previous
//
#include <hip/hip_runtime.h>
#include <math.h>

// EXACT round-11 kernel (PASSING, 60.6us) with ONE delta: plain stores
// instead of __builtin_nontemporal_store. Theory: nt bypasses L2 write
// aggregation; HBM needs ~KB-granular bursts, so 256-B nt wave-stores cost
// ~2x write efficiency. The fill kernel proves 7 TB/s THROUGH L2 at 10%
// occupancy. Input reuse no longer needs L2 protection (temporal-adjacency
// decode keeps chunk sharers co-resident; fetch ~30MB).
// Everything else byte-identical to r11 (C=16, 4 blocks/CU, same decode,
// same tap math, unclamped-base pair reads).
//
// out flat: ((((o*8 + gi)*128 + ic)*8 + j)*7 + u)*7 + v
// sig flat: ((o*128 + ic)*8 + d)*49 + h*7 + w

constexpr int BLOCK = 448;          // 7 waves; lanes 392..447 idle in compute
constexpr int JUV = 392;
constexpr int C = 16;               // channels per block (16 | 128 -> one 'o')
constexpr int PAD = 16;             // front/back pad floats

__global__ __launch_bounds__(BLOCK)
void lift15(const float* __restrict__ sig, float* __restrict__ out) {
  __shared__ __align__(16) float lds_raw[PAD + C * JUV + PAD];
  float* lds = lds_raw + PAD;

  const int bid   = blockIdx.x;
  const int gi    = (bid >> 3) & 7;                  // 0..7
  const int chunk = ((bid >> 6) << 3) | (bid & 7);   // 0..1023
  const int c0    = chunk * C;

  // ---- zero pads, then stage chunk with coalesced float4 ----
  if (threadIdx.x < PAD) {
    lds_raw[threadIdx.x] = 0.0f;
    lds_raw[PAD + C * JUV + threadIdx.x] = 0.0f;
  }
  {
    const float4* src4 = (const float4*)(sig + (size_t)c0 * JUV);
    float4* dst4 = (float4*)lds;
    for (int idx = threadIdx.x; idx < C * JUV / 4; idx += BLOCK)
      dst4[idx] = src4[idx];
  }
  __syncthreads();

  const int juv = threadIdx.x;
  if (juv >= JUV) return;

  int j  = juv / 49;
  int uv = juv - j * 49;
  int uu = uv / 7;
  int vv = uv - uu * 7;

  // ================= tap computation (verified math, rounds 2-11) ==========
  const float TWO_PI_F = 6.28318530717958647692f;
  const float STEP = TWO_PI_F / 8.0f;

  float ti = (float)gi * STEP;
  float tj = (float)j  * STEP;

  // ---- D (group) axis ----
  float tH = fmodf(tj - ti, TWO_PI_F);
  if (tH < 0.0f) tH += TWO_PI_F;
  const float largest = TWO_PI_F * 7.0f / 8.0f;
  float cD = 2.0f * tH / largest - 1.0f;
  float posD = (cD + 1.0f) * 0.5f * 7.0f;
  float flD = floorf(posD);
  float fd  = posD - flD;
  int dlo = (int)flD, dhi = dlo + 1;
  float wd0 = (dlo >= 0 && dlo <= 7) ? (1.0f - fd) : 0.0f;
  float wd1 = (dhi >= 0 && dhi <= 7) ? fd : 0.0f;
  int d0 = min(max(dlo, 0), 7) * 49;
  int d1 = min(max(dhi, 0), 7) * 49;

  // ---- rotation by inverse(e_i) ----
  float inv = fmodf(-ti, TWO_PI_F);
  if (inv < 0.0f) inv += TWO_PI_F;
  float cs = cosf(inv), sn = sinf(inv);
  float gx = (float)(uu - 3) * (1.0f / 3.0f);
  float gy = (float)(vv - 3) * (1.0f / 3.0f);
  float rx = cs * gx - sn * gy;
  float ry = sn * gx + cs * gy;

  // ---- H axis (rx) ----
  float posH = (rx + 1.0f) * 0.5f * 6.0f;
  float flH = floorf(posH);
  float fh  = posH - flH;
  int hlo = (int)flH, hhi = hlo + 1;
  float wh0 = (hlo >= 0 && hlo <= 6) ? (1.0f - fh) : 0.0f;
  float wh1 = (hhi >= 0 && hhi <= 6) ? fh : 0.0f;
  int h0 = min(max(hlo, 0), 6) * 7;
  int h1 = min(max(hhi, 0), 6) * 7;

  // ---- W axis (ry) ----
  float posW = (ry + 1.0f) * 0.5f * 6.0f;
  float flW = floorf(posW);
  float fw  = posW - flW;
  int wlo = (int)flW, whi = wlo + 1;
  float wq0 = (wlo >= 0 && wlo <= 6) ? (1.0f - fw) : 0.0f;
  float wq1 = (whi >= 0 && whi <= 6) ? fw : 0.0f;
  int q0 = min(max(wlo, 0), 6);
  int q1 = min(max(whi, 0), 6);
  // ==========================================================================

  // d-axis: dominant slice only (validated r4/r8-r11)
  float Wd; int db;
  if (wd1 > wd0) { Wd = wd1; db = d1; } else { Wd = wd0; db = d0; }

  const int o   = c0 >> 7;
  const int ic0 = c0 & 127;
  float* op = out + (size_t)((o * 8 + gi) * 128 + ic0) * JUV + juv;

  if ((gi & 1) == 0) {
    // exact grid symmetry: single dominant tap per spatial axis (validated)
    float Wh; int hb;
    if (wh1 > wh0) { Wh = wh1; hb = h1; } else { Wh = wh0; hb = h0; }
    float Ww; int qb;
    if (wq1 > wq0) { Ww = wq1; qb = q1; } else { Ww = wq0; qb = q0; }
    const float W = Wd * Wh * Ww;
    const int off = db + hb + qb;
    #pragma unroll
    for (int c = 0; c < C; ++c) {
      *op = lds[c * JUV + off] * W;
      op += JUV;
    }
  } else {
    // 2x2 spatial bilinear, unclamped-base pair reads (validated r10)
    const float w00 = Wd * wh0 * wq0, w01 = Wd * wh0 * wq1;
    const float w10 = Wd * wh1 * wq0, w11 = Wd * wh1 * wq1;
    const int b = db + hlo * 7 + wlo;    // unclamped; pads cover OOB
    #pragma unroll
    for (int c = 0; c < C; ++c) {
      const float* s = lds + c * JUV + b;
      *op = s[0] * w00 + s[1] * w01 + s[7] * w10 + s[8] * w11;
      op += JUV;
    }
  }
}

extern "C" void kernel_launch(void* const* d_in, const int* in_sizes, int n_in,
                              void* d_out, int out_size, void* d_ws, size_t ws_size,
                              hipStream_t stream) {
  const float* w = (const float*)d_in[0];
  float* out = (float*)d_out;
  const int blocks = 8 * (128 * 128 / C);   // 8192
  hipLaunchKernelGGL(lift15, dim3(blocks), dim3(BLOCK), 0, stream, w, out);
}

// Round 16
// 40.568 us; speedup vs baseline: 1.7533x; 1.1127x over previous
//
#include <hip/hip_runtime.h>
#include <math.h>

// r15 lineage (PASSING, 45.1us) + ONE delta: staging restructured as
// register-staged loads (each thread tid<392 loads 4x float4 = 1568 exact)
// with the tap trig computed BETWEEN load-issue and ds_write, so ~350cy of
// fmodf/cosf/sinf per thread overlaps the global-load latency instead of
// serializing after the barrier. (r14 tested this hoist confounded with
// C=32 occupancy regression; this isolates it at C=16 / 4 blocks/CU.)
// Everything else byte-identical to r15: plain stores (NT removal = the r15
// win), same decode (same-XCD + temporally-adjacent chunk sharers), same
// tap math, unclamped-base pair reads.
//
// out flat: ((((o*8 + gi)*128 + ic)*8 + j)*7 + u)*7 + v
// sig flat: ((o*128 + ic)*8 + d)*49 + h*7 + w

constexpr int BLOCK = 448;          // 7 waves; lanes 392..447 idle in compute
constexpr int JUV = 392;
constexpr int C = 16;               // channels per block (16 | 128 -> one 'o')
constexpr int PAD = 16;             // front/back pad floats

__global__ __launch_bounds__(BLOCK)
void lift16(const float* __restrict__ sig, float* __restrict__ out) {
  __shared__ __align__(16) float lds_raw[PAD + C * JUV + PAD];
  float* lds = lds_raw + PAD;

  const int bid   = blockIdx.x;
  const int gi    = (bid >> 3) & 7;                  // 0..7
  const int chunk = ((bid >> 6) << 3) | (bid & 7);   // 0..1023
  const int c0    = chunk * C;

  const int tid = threadIdx.x;
  const bool active = tid < JUV;

  // ---- issue staging loads FIRST (4x float4 per active thread, 1568 exact) --
  float4 sv0, sv1, sv2, sv3;
  {
    const float4* src4 = (const float4*)(sig + (size_t)c0 * JUV);
    if (active) {
      sv0 = src4[tid];
      sv1 = src4[tid + 392];
      sv2 = src4[tid + 784];
      sv3 = src4[tid + 1176];
    }
  }
  if (tid < PAD) {
    lds_raw[tid] = 0.0f;
    lds_raw[PAD + C * JUV + tid] = 0.0f;
  }

  // ---- tap computation while loads are in flight (independent of data) ----
  float eW = 0.0f, w00 = 0.0f, w01 = 0.0f, w10 = 0.0f, w11 = 0.0f;
  int eOff = 0, bb = 0;
  const bool even = (gi & 1) == 0;

  if (active) {
    const int juv = tid;
    int j  = juv / 49;
    int uv = juv - j * 49;
    int uu = uv / 7;
    int vv = uv - uu * 7;

    // ================= tap computation (verified math, rounds 2-15) ========
    const float TWO_PI_F = 6.28318530717958647692f;
    const float STEP = TWO_PI_F / 8.0f;

    float ti = (float)gi * STEP;
    float tj = (float)j  * STEP;

    // ---- D (group) axis ----
    float tH = fmodf(tj - ti, TWO_PI_F);
    if (tH < 0.0f) tH += TWO_PI_F;
    const float largest = TWO_PI_F * 7.0f / 8.0f;
    float cD = 2.0f * tH / largest - 1.0f;
    float posD = (cD + 1.0f) * 0.5f * 7.0f;
    float flD = floorf(posD);
    float fd  = posD - flD;
    int dlo = (int)flD, dhi = dlo + 1;
    float wd0 = (dlo >= 0 && dlo <= 7) ? (1.0f - fd) : 0.0f;
    float wd1 = (dhi >= 0 && dhi <= 7) ? fd : 0.0f;
    int d0 = min(max(dlo, 0), 7) * 49;
    int d1 = min(max(dhi, 0), 7) * 49;

    // ---- rotation by inverse(e_i) ----
    float inv = fmodf(-ti, TWO_PI_F);
    if (inv < 0.0f) inv += TWO_PI_F;
    float cs = cosf(inv), sn = sinf(inv);
    float gx = (float)(uu - 3) * (1.0f / 3.0f);
    float gy = (float)(vv - 3) * (1.0f / 3.0f);
    float rx = cs * gx - sn * gy;
    float ry = sn * gx + cs * gy;

    // ---- H axis (rx) ----
    float posH = (rx + 1.0f) * 0.5f * 6.0f;
    float flH = floorf(posH);
    float fh  = posH - flH;
    int hlo = (int)flH, hhi = hlo + 1;
    float wh0 = (hlo >= 0 && hlo <= 6) ? (1.0f - fh) : 0.0f;
    float wh1 = (hhi >= 0 && hhi <= 6) ? fh : 0.0f;
    int h0 = min(max(hlo, 0), 6) * 7;
    int h1 = min(max(hhi, 0), 6) * 7;

    // ---- W axis (ry) ----
    float posW = (ry + 1.0f) * 0.5f * 6.0f;
    float flW = floorf(posW);
    float fw  = posW - flW;
    int wlo = (int)flW, whi = wlo + 1;
    float wq0 = (wlo >= 0 && wlo <= 6) ? (1.0f - fw) : 0.0f;
    float wq1 = (whi >= 0 && whi <= 6) ? fw : 0.0f;
    int q0 = min(max(wlo, 0), 6);
    int q1 = min(max(whi, 0), 6);
    // ======================================================================

    // dominant d slice (validated r4/r8-r15)
    float Wd; int db;
    if (wd1 > wd0) { Wd = wd1; db = d1; } else { Wd = wd0; db = d0; }

    if (even) {
      float Wh; int hb;
      if (wh1 > wh0) { Wh = wh1; hb = h1; } else { Wh = wh0; hb = h0; }
      float Ww; int qb;
      if (wq1 > wq0) { Ww = wq1; qb = q1; } else { Ww = wq0; qb = q0; }
      eW   = Wd * Wh * Ww;
      eOff = db + hb + qb;
    } else {
      w00 = Wd * wh0 * wq0;  w01 = Wd * wh0 * wq1;
      w10 = Wd * wh1 * wq0;  w11 = Wd * wh1 * wq1;
      bb  = db + hlo * 7 + wlo;   // unclamped; pads cover OOB (validated r10)
    }
  }

  // ---- write staged data to LDS (waits on vmcnt here, after the trig) ----
  if (active) {
    float4* dst4 = (float4*)lds;
    dst4[tid]        = sv0;
    dst4[tid + 392]  = sv1;
    dst4[tid + 784]  = sv2;
    dst4[tid + 1176] = sv3;
  }
  __syncthreads();

  if (!active) return;
  const int juv = tid;

  const int o   = c0 >> 7;
  const int ic0 = c0 & 127;
  float* op = out + (size_t)((o * 8 + gi) * 128 + ic0) * JUV + juv;

  if (even) {
    #pragma unroll
    for (int c = 0; c < C; ++c) {
      *op = lds[c * JUV + eOff] * eW;
      op += JUV;
    }
  } else {
    #pragma unroll
    for (int c = 0; c < C; ++c) {
      const float* s = lds + c * JUV + bb;
      *op = s[0] * w00 + s[1] * w01 + s[7] * w10 + s[8] * w11;
      op += JUV;
    }
  }
}

extern "C" void kernel_launch(void* const* d_in, const int* in_sizes, int n_in,
                              void* d_out, int out_size, void* d_ws, size_t ws_size,
                              hipStream_t stream) {
  const float* w = (const float*)d_in[0];
  float* out = (float*)d_out;
  const int blocks = 8 * (128 * 128 / C);   // 8192
  hipLaunchKernelGGL(lift16, dim3(blocks), dim3(BLOCK), 0, stream, w, out);
}